// Round 2
// baseline (216.911 us; speedup 1.0000x reference)
//
#include <hip/hip_runtime.h>
#include <math.h>

// CrossAttention B=2,S=2048,E=1024,H=16,Dh=64,NC=768 — fp32 in/out.
// R9: (1) XCD-colocating swizzle for GEMM grids (bid%8 = m-tile%8 so the 8
// n-blocks sharing an A-tile land on one XCD's L2 — R8 gemm_qkv was L2-miss
// BW bound: FETCH 84.5 MB vs 19 unique, 2.33 TB/s = dispatch duration).
// Per-XCD set: 4 A-tiles (1MB) + B (2MB) < 4MB L2. (2) combine fused into
// gemm_out A-staging (p0+p1 scaled by precomputed inv[h], ds_write to same
// swizzled slots; B stays DMA) — one less dispatch, −24 MB traffic.
// attn/prep unchanged from R8.
// R10/R11: identical resubmits — R9/R10 benches hit GPUAcquisitionTimeout
// (broker at capacity, no data). Re-establish baseline + rocprof breakdown
// before spending any edit.

namespace {

typedef short bfr __attribute__((ext_vector_type(8)));   // 8 bf16 = 4 VGPR
typedef short s4v __attribute__((ext_vector_type(4)));
typedef unsigned u4v __attribute__((ext_vector_type(4)));
typedef float accf __attribute__((ext_vector_type(16)));

#define MFMA32(a, b, c) __builtin_amdgcn_mfma_f32_32x32x16_bf16(a, b, c, 0, 0, 0)

__device__ inline short f2bf(float f) {  // RNE
    unsigned u = __float_as_uint(f);
    u += 0x7fffu + ((u >> 16) & 1u);
    return (short)(u >> 16);
}
__device__ inline float bf2f(short s) {
    return __uint_as_float(((unsigned)(unsigned short)s) << 16);
}
__device__ inline float fexp2(float x) { return __builtin_amdgcn_exp2f(x); }
__device__ inline accf zero16() {
    accf z;
#pragma unroll
    for (int i = 0; i < 16; ++i) z[i] = 0.f;
    return z;
}
__device__ inline void dma16(const void* g, void* l) {
    __builtin_amdgcn_global_load_lds(
        (const __attribute__((address_space(1))) void*)g,
        (__attribute__((address_space(3))) void*)l, 16, 0, 0);
}

// ---------- prep: tobf (x,ctx) + all 4 weight transposes, one dispatch ----
__global__ __launch_bounds__(256) void prep(
    const float* __restrict__ x, const float* __restrict__ ctx,
    short* __restrict__ xb, short* __restrict__ cb,
    const float* __restrict__ Wq, const float* __restrict__ Wk,
    const float* __restrict__ Wv, const float* __restrict__ Wo,
    short* __restrict__ Wqt, short* __restrict__ Wkt,
    short* __restrict__ Wvt, short* __restrict__ Wot) {
    __shared__ short t[64][68];
    const int bx = blockIdx.x;
    if (bx < 7168) {  // elementwise fp32->bf16
        int i = bx * 256 + threadIdx.x;
        if (i < 1048576) {
            float4 v = ((const float4*)x)[i];
            s4v p = {f2bf(v.x), f2bf(v.y), f2bf(v.z), f2bf(v.w)};
            ((s4v*)xb)[i] = p;
        } else {
            int j = i - 1048576;
            float4 v = ((const float4*)ctx)[j];
            s4v p = {f2bf(v.x), f2bf(v.y), f2bf(v.z), f2bf(v.w)};
            ((s4v*)cb)[j] = p;
        }
        return;
    }
    const int idx = bx - 7168;  // 0..1023
    const int z = idx >> 8, gy = (idx >> 4) & 15, gx = idx & 15;
    const float* W;
    short* Wt;
    int K;
    switch (z) {
        case 0: W = Wq; Wt = Wqt; K = 1024; break;
        case 1: W = Wk; Wt = Wkt; K = 768; break;
        case 2: W = Wv; Wt = Wvt; K = 768; break;
        default: W = Wo; Wt = Wot; K = 1024; break;
    }
    const int k0 = gy * 64;
    if (k0 >= K) return;
    const int tid = threadIdx.x;
    const int n0 = gx * 64;
    const int kr = tid >> 4, nc = (tid & 15) * 4;
#pragma unroll
    for (int rep = 0; rep < 4; ++rep) {
        int k = kr + rep * 16;
        float4 v = *(const float4*)&W[(size_t)(k0 + k) * 1024 + n0 + nc];
        t[nc + 0][k] = f2bf(v.x);
        t[nc + 1][k] = f2bf(v.y);
        t[nc + 2][k] = f2bf(v.z);
        t[nc + 3][k] = f2bf(v.w);
    }
    __syncthreads();
    const int nr = tid >> 4, kc = (tid & 15) * 4;
#pragma unroll
    for (int rep = 0; rep < 4; ++rep) {
        int n = nr + rep * 16;
        s4v p = {t[n][kc], t[n][kc + 1], t[n][kc + 2], t[n][kc + 3]};
        *(s4v*)&Wt[(size_t)(n0 + n) * K + k0 + kc] = p;
    }
}

// ---------- fused Q/K/V projection GEMM, XCD-swizzled 1D grid (768) -------
// bid: z = bid>>8; local = bid&255; m = local&31, n = local>>5
// -> bid%8 == m%8: the 8 n-blocks sharing an A-tile colocate on one XCD.
__global__ __launch_bounds__(256) void gemm_qkv(
    const short* __restrict__ xb, const short* __restrict__ cb,
    const short* __restrict__ Wqt, const short* __restrict__ Wkt,
    const short* __restrict__ Wvt, const float* __restrict__ bq,
    const float* __restrict__ bk, const float* __restrict__ bv,
    short* __restrict__ Qf, short* __restrict__ Kf, short* __restrict__ Vt,
    float qscale) {
    const int bid = blockIdx.x;
    const int z = bid >> 8;
    const int local = bid & 255;
    const short* A  = (z == 0) ? xb : cb;
    const short* Bt = (z == 0) ? Wqt : ((z == 1) ? Wkt : Wvt);
    const float* bias = (z == 0) ? bq : ((z == 1) ? bk : bv);
    const int K = (z == 0) ? 1024 : 768;
    const int NIT = K / 32;
    const float scale = (z == 0) ? qscale : 1.f;
    short* out = (z == 0) ? Qf : ((z == 1) ? Kf : Vt);

    __shared__ short As[8192];  // 2 x 4096 (double buffer)
    __shared__ short Bs[8192];
    const int t = threadIdx.x, lane = t & 63, w = t >> 6;
    const int lm = lane & 31, h2 = lane >> 5;
    const int wm = w & 1, wn = w >> 1;
    const int m0 = (local & 31) * 128, n0 = (local >> 5) * 128;

    // staging: slot t holds global chunk sigma(t) = t ^ ((t>>3)&7)
    const int st = t ^ ((t >> 3) & 7);
    const int srow = st >> 2, scol = (st & 3) * 8;
    const short* ga = A + (size_t)(m0 + srow) * K + scol;
    const short* gb = Bt + (size_t)(n0 + srow) * K + scol;

    // read: slot = chunk ^ xorv, chunk = row*4 + colchunk
    const int xorv = (lm >> 1) & 7;
    const int rA0 = wm * 64 + lm, rB0 = wn * 64 + lm;

    accf acc[2][2] = {zero16(), zero16(), zero16(), zero16()};

    // prologue: stage iter 0 into buf 0
    dma16(ga, &As[w * 512]);
    dma16(ga + (size_t)64 * K, &As[2048 + w * 512]);
    dma16(gb, &Bs[w * 512]);
    dma16(gb + (size_t)64 * K, &Bs[2048 + w * 512]);

#pragma unroll 1
    for (int it = 0; it < NIT; ++it) {
        const int p = it & 1;
        __syncthreads();  // drains DMA for buf p (vmcnt0 before s_barrier)
        if (it + 1 < NIT) {
            const int kt = (it + 1) * 32;
            short* lA = &As[(1 - p) * 4096 + w * 512];
            short* lB = &Bs[(1 - p) * 4096 + w * 512];
            dma16(ga + kt, lA);
            dma16(ga + (size_t)64 * K + kt, lA + 2048);
            dma16(gb + kt, lB);
            dma16(gb + (size_t)64 * K + kt, lB + 2048);
        }
        const short* bA = &As[p * 4096];
        const short* bB = &Bs[p * 4096];
#pragma unroll
        for (int kk8 = 0; kk8 < 4; kk8 += 2) {
            bfr a0 = *(const bfr*)&bA[((rA0 * 4 + h2 + kk8) ^ xorv) * 8];
            bfr a1 = *(const bfr*)&bA[(((rA0 + 32) * 4 + h2 + kk8) ^ xorv) * 8];
            bfr b0 = *(const bfr*)&bB[((rB0 * 4 + h2 + kk8) ^ xorv) * 8];
            bfr b1 = *(const bfr*)&bB[(((rB0 + 32) * 4 + h2 + kk8) ^ xorv) * 8];
            acc[0][0] = MFMA32(a0, b0, acc[0][0]);
            acc[0][1] = MFMA32(a0, b1, acc[0][1]);
            acc[1][0] = MFMA32(a1, b0, acc[1][0]);
            acc[1][1] = MFMA32(a1, b1, acc[1][1]);
        }
    }

#pragma unroll
    for (int nt = 0; nt < 2; ++nt) {
        const int n = n0 + wn * 64 + nt * 32 + lm;
        const float bn = bias[n];
        const int hh = n >> 6, dd = n & 63;
#pragma unroll
        for (int mt = 0; mt < 2; ++mt) {
            const int mbase = m0 + wm * 64 + mt * 32 + 4 * h2;
            if (z != 2) {
                const int cb2 = (dd >> 4) * 512 + ((dd >> 3) & 1) * 256 + (dd & 7);
#pragma unroll
                for (int r = 0; r < 16; ++r) {
                    const int m = mbase + (r & 3) + 8 * (r >> 2);
                    const int bb = m >> 11, q = m & 2047;
                    float v = (acc[mt][nt][r] + bn) * scale;
                    out[((size_t)((bb * 16 + hh) * 64 + (q >> 5))) * 2048 +
                        cb2 + (q & 31) * 8] = f2bf(v);
                }
            } else {
                const int dblk = dd >> 5, lmv = dd & 31;
#pragma unroll
                for (int g = 0; g < 4; ++g) {
                    const int m = mbase + 8 * g;
                    const int bb = m >> 11, s = m & 2047;
                    const int kvt = s >> 6, kc = (s >> 4) & 3;
                    const int h2v = (s >> 3) & 1, j0 = s & 7;
                    s4v p = {f2bf(acc[mt][nt][4 * g + 0] + bn),
                             f2bf(acc[mt][nt][4 * g + 1] + bn),
                             f2bf(acc[mt][nt][4 * g + 2] + bn),
                             f2bf(acc[mt][nt][4 * g + 3] + bn)};
                    *(s4v*)(out +
                            ((size_t)(((bb * 16 + hh) * 32 + kvt) * 2 + dblk)) * 2048 +
                            kc * 512 + h2v * 256 + lmv * 8 + j0) = p;
                }
            }
        }
    }
}

// ---------- output GEMM with fused combine (512 thr, 8 waves) ----------
// A-tile = (p0+p1)*inv staged via explicit loads + ds_write (same swizzled
// slots); B via DMA. 1D grid 256, XCD swizzle m = bid&31.
__global__ __launch_bounds__(512) void gemm_out(
    const short* __restrict__ p0, const short* __restrict__ p1,
    const float* __restrict__ lsum, const short* __restrict__ Bt,
    const float* __restrict__ bias, float* __restrict__ out) {
    constexpr int K = 1024, NIT = 32;
    __shared__ short As[8192];  // 2 x 4096
    __shared__ short Bs[8192];
    const int t = threadIdx.x, lane = t & 63, w = t >> 6;  // w 0..7
    const int lm = lane & 31, h2 = lane >> 5;
    const int wm = w & 1, wn = w >> 1;
    const int bid = blockIdx.x;
    const int m0 = (bid & 31) * 128, n0 = (bid >> 5) * 128;

    const int st = t ^ ((t >> 3) & 7);
    const int srow = st >> 2, scol = (st & 3) * 8;  // 512 thr cover full tile
    const int gm = m0 + srow;
    const int b = gm >> 11, q = gm & 2047;
    const short* pa0 = p0 + (size_t)gm * 1024 + scol;
    const short* pa1 = p1 + (size_t)gm * 1024 + scol;
    const short* gb = Bt + (size_t)(n0 + srow) * K + scol;

    float inv[16];
#pragma unroll
    for (int h = 0; h < 16; ++h) {
        float l0 = lsum[((size_t)b * 16 + h) * 2048 + q];
        float l1 = lsum[((size_t)(2 + b) * 16 + h) * 2048 + q];
        inv[h] = 1.f / (l0 + l1);
    }

    const int xorv = (lm >> 1) & 7;
    const int rA0 = wm * 64 + lm, rB0 = wn * 32 + lm;

    accf acc[2] = {zero16(), zero16()};

    // prologue: stage iter 0 (B via DMA, A via load+combine+ds_write)
    dma16(gb, &Bs[w * 512]);
    {
        bfr v0 = *(const bfr*)pa0;
        bfr v1 = *(const bfr*)pa1;
        const float iv = inv[0];
        bfr pk;
#pragma unroll
        for (int j = 0; j < 8; ++j)
            pk[j] = f2bf((bf2f(v0[j]) + bf2f(v1[j])) * iv);
        *(bfr*)&As[t * 8] = pk;
    }

#pragma unroll 1
    for (int it = 0; it < NIT; ++it) {
        const int p = it & 1;
        __syncthreads();  // drains buf-p DMA + ds_writes
        bfr v0, v1;
        const bool nxt = (it + 1 < NIT);
        if (nxt) {
            const int ktn = (it + 1) * 32;
            dma16(gb + ktn, &Bs[(1 - p) * 4096 + w * 512]);
            v0 = *(const bfr*)(pa0 + ktn);
            v1 = *(const bfr*)(pa1 + ktn);
        }
        const short* bA = &As[p * 4096];
        const short* bB = &Bs[p * 4096];
#pragma unroll
        for (int kk8 = 0; kk8 < 4; kk8 += 2) {
            bfr a0 = *(const bfr*)&bA[((rA0 * 4 + h2 + kk8) ^ xorv) * 8];
            bfr a1 = *(const bfr*)&bA[(((rA0 + 32) * 4 + h2 + kk8) ^ xorv) * 8];
            bfr b0 = *(const bfr*)&bB[((rB0 * 4 + h2 + kk8) ^ xorv) * 8];
            acc[0] = MFMA32(a0, b0, acc[0]);
            acc[1] = MFMA32(a1, b0, acc[1]);
        }
        if (nxt) {
            const float iv = inv[(it + 1) >> 1];  // h = kt>>6, iter-uniform
            bfr pk;
#pragma unroll
            for (int j = 0; j < 8; ++j)
                pk[j] = f2bf((bf2f(v0[j]) + bf2f(v1[j])) * iv);
            *(bfr*)&As[(1 - p) * 4096 + t * 8] = pk;
        }
    }

    const int n = n0 + wn * 32 + lm;
    const float bn = bias[n];
#pragma unroll
    for (int mt = 0; mt < 2; ++mt) {
        const int mbase = m0 + wm * 64 + mt * 32 + 4 * h2;
#pragma unroll
        for (int r = 0; r < 16; ++r) {
            const int m = mbase + (r & 3) + 8 * (r >> 2);
            out[(size_t)m * 1024 + n] = acc[mt][r] + bn;
        }
    }
}

// ---------- flash attention: LDS-staged K/V + KV-split x2 (unchanged) -----
__global__ __launch_bounds__(256, 3) void attn(
    const short* __restrict__ Qf, const short* __restrict__ Kf,
    const short* __restrict__ Vt, short* __restrict__ part,
    float* __restrict__ lsum) {
    __shared__ short smem[16384];  // 2 bufs x (K 4KB + V 4KB) = 32 KB
    const int bid = blockIdx.x;
    const int hidx = bid & 31, qs = bid >> 5;
    const int split = qs & 1, qb = qs >> 1;
    const int b = hidx >> 4, h = hidx & 15;
    const int lane = threadIdx.x & 63, wv = threadIdx.x >> 6;
    const int lm = lane & 31, h2 = lane >> 5;
    const bool hb = h2 != 0;
    const int q0 = qb * 128 + wv * 32;

    const short* qbase =
        Qf + ((size_t)(hidx * 64 + (q0 >> 5))) * 2048 + lane * 8;
    bfr qf[4];
#pragma unroll
    for (int kc = 0; kc < 4; ++kc) qf[kc] = *(const bfr*)(qbase + kc * 512);

    const short* khead = Kf + (size_t)hidx * 131072 + split * 65536;
    const short* vhead = Vt + (size_t)hidx * 131072 + split * 65536;
    const short* gsrc =
        ((wv < 2) ? (khead + wv * 2048) : (vhead + (wv - 2) * 2048)) + lane * 8;

#pragma unroll
    for (int i = 0; i < 4; ++i)
        dma16(gsrc + i * 512, &smem[wv * 2048 + i * 512]);

    accf oa0 = zero16(), oa1 = zero16();
    float la0 = 0.f, la1 = 0.f;

#pragma unroll 1
    for (int it = 0; it < 16; ++it) {
        const int p = it & 1;
        __syncthreads();  // buf p DMA drained (vmcnt(0) before s_barrier)
        if (it + 1 < 16) {
            const short* gn = gsrc + (size_t)(it + 1) * 4096;
            short* ln = &smem[(1 - p) * 8192 + wv * 2048];
#pragma unroll
            for (int i = 0; i < 4; ++i) dma16(gn + i * 512, ln + i * 512);
        }
        const short* kb = &smem[p * 8192];
        bfr kf0[4], kf1[4], vf0[4], vf1[4];
#pragma unroll
        for (int kc = 0; kc < 4; ++kc) {
            kf0[kc] = *(const bfr*)&kb[kc * 512 + lane * 8];
            kf1[kc] = *(const bfr*)&kb[2048 + kc * 512 + lane * 8];
            vf0[kc] = *(const bfr*)&kb[4096 + kc * 512 + lane * 8];
            vf1[kc] = *(const bfr*)&kb[6144 + kc * 512 + lane * 8];
        }
        accf s0 = zero16(), s1 = zero16();
#pragma unroll
        for (int kc = 0; kc < 4; ++kc) {
            s0 = MFMA32(kf0[kc], qf[kc], s0);
            s1 = MFMA32(kf1[kc], qf[kc], s1);
        }

#pragma unroll
        for (int i = 0; i < 16; ++i) s0[i] = fexp2(s0[i]);
#pragma unroll
        for (int i = 0; i < 16; ++i) s1[i] = fexp2(s1[i]);
#pragma unroll
        for (int i = 0; i < 16; ++i) {
            if (i & 1) la1 += s0[i] + s1[i];
            else       la0 += s0[i] + s1[i];
        }

        // packed half-swap transpose
        bfr pb[4];
#pragma unroll
        for (int kc = 0; kc < 4; ++kc) {
            const accf& s = (kc < 2) ? s0 : s1;
            const int base = 8 * (kc & 1);
            unsigned Lw0 = __builtin_amdgcn_perm(__float_as_uint(s[base + 1]),
                                                 __float_as_uint(s[base + 0]),
                                                 0x07060302u);
            unsigned Lw1 = __builtin_amdgcn_perm(__float_as_uint(s[base + 3]),
                                                 __float_as_uint(s[base + 2]),
                                                 0x07060302u);
            unsigned Hw0 = __builtin_amdgcn_perm(__float_as_uint(s[base + 5]),
                                                 __float_as_uint(s[base + 4]),
                                                 0x07060302u);
            unsigned Hw1 = __builtin_amdgcn_perm(__float_as_uint(s[base + 7]),
                                                 __float_as_uint(s[base + 6]),
                                                 0x07060302u);
            unsigned c0 = hb ? Lw0 : Hw0;
            unsigned c1 = hb ? Lw1 : Hw1;
            unsigned r0 = (unsigned)__shfl_xor((int)c0, 32);
            unsigned r1 = (unsigned)__shfl_xor((int)c1, 32);
            u4v pw = {hb ? r0 : Lw0, hb ? r1 : Lw1,
                      hb ? Hw0 : r0, hb ? Hw1 : r1};
            pb[kc] = __builtin_bit_cast(bfr, pw);
        }

#pragma unroll
        for (int kc = 0; kc < 4; ++kc) {
            oa0 = MFMA32(vf0[kc], pb[kc], oa0);
            oa1 = MFMA32(vf1[kc], pb[kc], oa1);
        }
    }

    float ls = la0 + la1;
    ls += __shfl_xor(ls, 32);
    if (!hb) lsum[((size_t)(split * 2 + b) * 16 + h) * 2048 + q0 + lm] = ls;

    short* orow = part + (size_t)split * 4194304 +
                  (size_t)(b * 2048 + q0 + lm) * 1024 + h * 64;
#pragma unroll
    for (int dt = 0; dt < 2; ++dt) {
        const accf& oa = dt ? oa1 : oa0;
#pragma unroll
        for (int g = 0; g < 4; ++g) {
            const int d0 = dt * 32 + 4 * h2 + 8 * g;
            s4v p = {f2bf(oa[4 * g + 0]), f2bf(oa[4 * g + 1]),
                     f2bf(oa[4 * g + 2]), f2bf(oa[4 * g + 3])};
            *(s4v*)(orow + d0) = p;
        }
    }
}

}  // namespace

extern "C" void kernel_launch(void* const* d_in, const int* in_sizes, int n_in,
                              void* d_out, int out_size, void* d_ws,
                              size_t ws_size, hipStream_t stream) {
    const float* x   = (const float*)d_in[0];
    const float* ctx = (const float*)d_in[1];
    const float* Wq  = (const float*)d_in[2];
    const float* bq  = (const float*)d_in[3];
    const float* Wk  = (const float*)d_in[4];
    const float* bk  = (const float*)d_in[5];
    const float* Wv  = (const float*)d_in[6];
    const float* bv  = (const float*)d_in[7];
    const float* Wo  = (const float*)d_in[8];
    const float* bo  = (const float*)d_in[9];

    short* xb  = (short*)d_ws;
    short* cb  = xb + (size_t)4096 * 1024;
    short* Wqt = cb + (size_t)4096 * 768;
    short* Wkt = Wqt + (size_t)1024 * 1024;
    short* Wvt = Wkt + (size_t)1024 * 768;
    short* Wot = Wvt + (size_t)1024 * 768;
    short* Qf  = Wot + (size_t)1024 * 1024;  // frag-order, pre-scaled
    short* Kf  = Qf + (size_t)4096 * 1024;   // frag-order
    short* Vt  = Kf + (size_t)4096 * 1024;   // frag-order V^T
    short* p0  = Vt + (size_t)4096 * 1024;   // split partials (unnormalized)
    short* p1  = p0 + (size_t)4096 * 1024;
    float* lsum = (float*)(p1 + (size_t)4096 * 1024);  // [2][2][16][2048]

    prep<<<8192, 256, 0, stream>>>(x, ctx, xb, cb, Wq, Wk, Wv, Wo,
                                   Wqt, Wkt, Wvt, Wot);

    const float qscale = 0.125f * 1.44269504088896f;
    gemm_qkv<<<768, 256, 0, stream>>>(xb, cb, Wqt, Wkt, Wvt,
                                      bq, bk, bv, Qf, Kf, Vt, qscale);

    attn<<<1024, 256, 0, stream>>>(Qf, Kf, Vt, p0, lsum);

    gemm_out<<<256, 512, 0, stream>>>(p0, p1, lsum, Wot, bo, (float*)d_out);
}

// Round 6
// 216.396 us; speedup vs baseline: 1.0024x; 1.0024x over previous
//
#include <hip/hip_runtime.h>
#include <math.h>

// CrossAttention B=2,S=2048,E=1024,H=16,Dh=64,NC=768 — fp32 in/out.
// R9: XCD-colocating swizzle for GEMM grids + combine fused into gemm_out.
// R12/R13: attn rewritten as 4-buffer counted-vmcnt pipeline (T3/T4):
//   - 32-row KV tiles (8KB/buf x 4 = 32KB LDS, same total as before), 32 iters
//   - per iter: s_waitcnt vmcnt(4) -> raw s_barrier (NO vmcnt(0) drain) ->
//     issue DMA for it+3 -> compute. DMA lead = 3 iters (~750+ cyc) >= L2/L3
//     latency; loads stay in flight across barriers.
//   - tail uniformity: batches wrap ((it+3)&31) into already-free buffers
//     (buf((it+3)&3) last read at iter it-1, before this barrier) so
//     vmcnt(4) is exact every iteration.
//   - R13 fix (pre-first-run audit): s_waitcnt vmcnt(0) after the loop —
//     kernel must not end with LDS-DMA in flight (LDS can be reallocated to
//     a new block; late DMA writes would corrupt it).
//   Rationale: R11 counters — attn 46.4us, MfmaUtil 30%, VALUBusy 39%,
//   occupancy 28%, 0 bank conflicts, HBM 8% => barrier-drain latency bound
//   (the __syncthreads vmcnt(0) drain each iter). prep/gemms unchanged.
// R14/R15: identical resubmits — broker at capacity rounds 3-5; this version
//   has never executed. Fourth static audit (K/V frag-layout chain, vmcnt
//   ledger, buffer-reuse windows) found no defect. No blind edits.

namespace {

typedef short bfr __attribute__((ext_vector_type(8)));   // 8 bf16 = 4 VGPR
typedef short s4v __attribute__((ext_vector_type(4)));
typedef unsigned u4v __attribute__((ext_vector_type(4)));
typedef float accf __attribute__((ext_vector_type(16)));

#define MFMA32(a, b, c) __builtin_amdgcn_mfma_f32_32x32x16_bf16(a, b, c, 0, 0, 0)

__device__ inline short f2bf(float f) {  // RNE
    unsigned u = __float_as_uint(f);
    u += 0x7fffu + ((u >> 16) & 1u);
    return (short)(u >> 16);
}
__device__ inline float bf2f(short s) {
    return __uint_as_float(((unsigned)(unsigned short)s) << 16);
}
__device__ inline float fexp2(float x) { return __builtin_amdgcn_exp2f(x); }
__device__ inline accf zero16() {
    accf z;
#pragma unroll
    for (int i = 0; i < 16; ++i) z[i] = 0.f;
    return z;
}
__device__ inline void dma16(const void* g, void* l) {
    __builtin_amdgcn_global_load_lds(
        (const __attribute__((address_space(1))) void*)g,
        (__attribute__((address_space(3))) void*)l, 16, 0, 0);
}

// ---------- prep: tobf (x,ctx) + all 4 weight transposes, one dispatch ----
__global__ __launch_bounds__(256) void prep(
    const float* __restrict__ x, const float* __restrict__ ctx,
    short* __restrict__ xb, short* __restrict__ cb,
    const float* __restrict__ Wq, const float* __restrict__ Wk,
    const float* __restrict__ Wv, const float* __restrict__ Wo,
    short* __restrict__ Wqt, short* __restrict__ Wkt,
    short* __restrict__ Wvt, short* __restrict__ Wot) {
    __shared__ short t[64][68];
    const int bx = blockIdx.x;
    if (bx < 7168) {  // elementwise fp32->bf16
        int i = bx * 256 + threadIdx.x;
        if (i < 1048576) {
            float4 v = ((const float4*)x)[i];
            s4v p = {f2bf(v.x), f2bf(v.y), f2bf(v.z), f2bf(v.w)};
            ((s4v*)xb)[i] = p;
        } else {
            int j = i - 1048576;
            float4 v = ((const float4*)ctx)[j];
            s4v p = {f2bf(v.x), f2bf(v.y), f2bf(v.z), f2bf(v.w)};
            ((s4v*)cb)[j] = p;
        }
        return;
    }
    const int idx = bx - 7168;  // 0..1023
    const int z = idx >> 8, gy = (idx >> 4) & 15, gx = idx & 15;
    const float* W;
    short* Wt;
    int K;
    switch (z) {
        case 0: W = Wq; Wt = Wqt; K = 1024; break;
        case 1: W = Wk; Wt = Wkt; K = 768; break;
        case 2: W = Wv; Wt = Wvt; K = 768; break;
        default: W = Wo; Wt = Wot; K = 1024; break;
    }
    const int k0 = gy * 64;
    if (k0 >= K) return;
    const int tid = threadIdx.x;
    const int n0 = gx * 64;
    const int kr = tid >> 4, nc = (tid & 15) * 4;
#pragma unroll
    for (int rep = 0; rep < 4; ++rep) {
        int k = kr + rep * 16;
        float4 v = *(const float4*)&W[(size_t)(k0 + k) * 1024 + n0 + nc];
        t[nc + 0][k] = f2bf(v.x);
        t[nc + 1][k] = f2bf(v.y);
        t[nc + 2][k] = f2bf(v.z);
        t[nc + 3][k] = f2bf(v.w);
    }
    __syncthreads();
    const int nr = tid >> 4, kc = (tid & 15) * 4;
#pragma unroll
    for (int rep = 0; rep < 4; ++rep) {
        int n = nr + rep * 16;
        s4v p = {t[n][kc], t[n][kc + 1], t[n][kc + 2], t[n][kc + 3]};
        *(s4v*)&Wt[(size_t)(n0 + n) * K + k0 + kc] = p;
    }
}

// ---------- fused Q/K/V projection GEMM, XCD-swizzled 1D grid (768) -------
// bid: z = bid>>8; local = bid&255; m = local&31, n = local>>5
// -> bid%8 == m%8: the 8 n-blocks sharing an A-tile colocate on one XCD.
__global__ __launch_bounds__(256) void gemm_qkv(
    const short* __restrict__ xb, const short* __restrict__ cb,
    const short* __restrict__ Wqt, const short* __restrict__ Wkt,
    const short* __restrict__ Wvt, const float* __restrict__ bq,
    const float* __restrict__ bk, const float* __restrict__ bv,
    short* __restrict__ Qf, short* __restrict__ Kf, short* __restrict__ Vt,
    float qscale) {
    const int bid = blockIdx.x;
    const int z = bid >> 8;
    const int local = bid & 255;
    const short* A  = (z == 0) ? xb : cb;
    const short* Bt = (z == 0) ? Wqt : ((z == 1) ? Wkt : Wvt);
    const float* bias = (z == 0) ? bq : ((z == 1) ? bk : bv);
    const int K = (z == 0) ? 1024 : 768;
    const int NIT = K / 32;
    const float scale = (z == 0) ? qscale : 1.f;
    short* out = (z == 0) ? Qf : ((z == 1) ? Kf : Vt);

    __shared__ short As[8192];  // 2 x 4096 (double buffer)
    __shared__ short Bs[8192];
    const int t = threadIdx.x, lane = t & 63, w = t >> 6;
    const int lm = lane & 31, h2 = lane >> 5;
    const int wm = w & 1, wn = w >> 1;
    const int m0 = (local & 31) * 128, n0 = (local >> 5) * 128;

    // staging: slot t holds global chunk sigma(t) = t ^ ((t>>3)&7)
    const int st = t ^ ((t >> 3) & 7);
    const int srow = st >> 2, scol = (st & 3) * 8;
    const short* ga = A + (size_t)(m0 + srow) * K + scol;
    const short* gb = Bt + (size_t)(n0 + srow) * K + scol;

    // read: slot = chunk ^ xorv, chunk = row*4 + colchunk
    const int xorv = (lm >> 1) & 7;
    const int rA0 = wm * 64 + lm, rB0 = wn * 64 + lm;

    accf acc[2][2] = {zero16(), zero16(), zero16(), zero16()};

    // prologue: stage iter 0 into buf 0
    dma16(ga, &As[w * 512]);
    dma16(ga + (size_t)64 * K, &As[2048 + w * 512]);
    dma16(gb, &Bs[w * 512]);
    dma16(gb + (size_t)64 * K, &Bs[2048 + w * 512]);

#pragma unroll 1
    for (int it = 0; it < NIT; ++it) {
        const int p = it & 1;
        __syncthreads();  // drains DMA for buf p (vmcnt0 before s_barrier)
        if (it + 1 < NIT) {
            const int kt = (it + 1) * 32;
            short* lA = &As[(1 - p) * 4096 + w * 512];
            short* lB = &Bs[(1 - p) * 4096 + w * 512];
            dma16(ga + kt, lA);
            dma16(ga + (size_t)64 * K + kt, lA + 2048);
            dma16(gb + kt, lB);
            dma16(gb + (size_t)64 * K + kt, lB + 2048);
        }
        const short* bA = &As[p * 4096];
        const short* bB = &Bs[p * 4096];
#pragma unroll
        for (int kk8 = 0; kk8 < 4; kk8 += 2) {
            bfr a0 = *(const bfr*)&bA[((rA0 * 4 + h2 + kk8) ^ xorv) * 8];
            bfr a1 = *(const bfr*)&bA[(((rA0 + 32) * 4 + h2 + kk8) ^ xorv) * 8];
            bfr b0 = *(const bfr*)&bB[((rB0 * 4 + h2 + kk8) ^ xorv) * 8];
            bfr b1 = *(const bfr*)&bB[(((rB0 + 32) * 4 + h2 + kk8) ^ xorv) * 8];
            acc[0][0] = MFMA32(a0, b0, acc[0][0]);
            acc[0][1] = MFMA32(a0, b1, acc[0][1]);
            acc[1][0] = MFMA32(a1, b0, acc[1][0]);
            acc[1][1] = MFMA32(a1, b1, acc[1][1]);
        }
    }

#pragma unroll
    for (int nt = 0; nt < 2; ++nt) {
        const int n = n0 + wn * 64 + nt * 32 + lm;
        const float bn = bias[n];
        const int hh = n >> 6, dd = n & 63;
#pragma unroll
        for (int mt = 0; mt < 2; ++mt) {
            const int mbase = m0 + wm * 64 + mt * 32 + 4 * h2;
            if (z != 2) {
                const int cb2 = (dd >> 4) * 512 + ((dd >> 3) & 1) * 256 + (dd & 7);
#pragma unroll
                for (int r = 0; r < 16; ++r) {
                    const int m = mbase + (r & 3) + 8 * (r >> 2);
                    const int bb = m >> 11, q = m & 2047;
                    float v = (acc[mt][nt][r] + bn) * scale;
                    out[((size_t)((bb * 16 + hh) * 64 + (q >> 5))) * 2048 +
                        cb2 + (q & 31) * 8] = f2bf(v);
                }
            } else {
                const int dblk = dd >> 5, lmv = dd & 31;
#pragma unroll
                for (int g = 0; g < 4; ++g) {
                    const int m = mbase + 8 * g;
                    const int bb = m >> 11, s = m & 2047;
                    const int kvt = s >> 6, kc = (s >> 4) & 3;
                    const int h2v = (s >> 3) & 1, j0 = s & 7;
                    s4v p = {f2bf(acc[mt][nt][4 * g + 0] + bn),
                             f2bf(acc[mt][nt][4 * g + 1] + bn),
                             f2bf(acc[mt][nt][4 * g + 2] + bn),
                             f2bf(acc[mt][nt][4 * g + 3] + bn)};
                    *(s4v*)(out +
                            ((size_t)(((bb * 16 + hh) * 32 + kvt) * 2 + dblk)) * 2048 +
                            kc * 512 + h2v * 256 + lmv * 8 + j0) = p;
                }
            }
        }
    }
}

// ---------- output GEMM with fused combine (512 thr, 8 waves) ----------
// A-tile = (p0+p1)*inv staged via explicit loads + ds_write (same swizzled
// slots); B via DMA. 1D grid 256, XCD swizzle m = bid&31.
__global__ __launch_bounds__(512) void gemm_out(
    const short* __restrict__ p0, const short* __restrict__ p1,
    const float* __restrict__ lsum, const short* __restrict__ Bt,
    const float* __restrict__ bias, float* __restrict__ out) {
    constexpr int K = 1024, NIT = 32;
    __shared__ short As[8192];  // 2 x 4096
    __shared__ short Bs[8192];
    const int t = threadIdx.x, lane = t & 63, w = t >> 6;  // w 0..7
    const int lm = lane & 31, h2 = lane >> 5;
    const int wm = w & 1, wn = w >> 1;
    const int bid = blockIdx.x;
    const int m0 = (bid & 31) * 128, n0 = (bid >> 5) * 128;

    const int st = t ^ ((t >> 3) & 7);
    const int srow = st >> 2, scol = (st & 3) * 8;  // 512 thr cover full tile
    const int gm = m0 + srow;
    const int b = gm >> 11, q = gm & 2047;
    const short* pa0 = p0 + (size_t)gm * 1024 + scol;
    const short* pa1 = p1 + (size_t)gm * 1024 + scol;
    const short* gb = Bt + (size_t)(n0 + srow) * K + scol;

    float inv[16];
#pragma unroll
    for (int h = 0; h < 16; ++h) {
        float l0 = lsum[((size_t)b * 16 + h) * 2048 + q];
        float l1 = lsum[((size_t)(2 + b) * 16 + h) * 2048 + q];
        inv[h] = 1.f / (l0 + l1);
    }

    const int xorv = (lm >> 1) & 7;
    const int rA0 = wm * 64 + lm, rB0 = wn * 32 + lm;

    accf acc[2] = {zero16(), zero16()};

    // prologue: stage iter 0 (B via DMA, A via load+combine+ds_write)
    dma16(gb, &Bs[w * 512]);
    {
        bfr v0 = *(const bfr*)pa0;
        bfr v1 = *(const bfr*)pa1;
        const float iv = inv[0];
        bfr pk;
#pragma unroll
        for (int j = 0; j < 8; ++j)
            pk[j] = f2bf((bf2f(v0[j]) + bf2f(v1[j])) * iv);
        *(bfr*)&As[t * 8] = pk;
    }

#pragma unroll 1
    for (int it = 0; it < NIT; ++it) {
        const int p = it & 1;
        __syncthreads();  // drains buf-p DMA + ds_writes
        bfr v0, v1;
        const bool nxt = (it + 1 < NIT);
        if (nxt) {
            const int ktn = (it + 1) * 32;
            dma16(gb + ktn, &Bs[(1 - p) * 4096 + w * 512]);
            v0 = *(const bfr*)(pa0 + ktn);
            v1 = *(const bfr*)(pa1 + ktn);
        }
        const short* bA = &As[p * 4096];
        const short* bB = &Bs[p * 4096];
#pragma unroll
        for (int kk8 = 0; kk8 < 4; kk8 += 2) {
            bfr a0 = *(const bfr*)&bA[((rA0 * 4 + h2 + kk8) ^ xorv) * 8];
            bfr a1 = *(const bfr*)&bA[(((rA0 + 32) * 4 + h2 + kk8) ^ xorv) * 8];
            bfr b0 = *(const bfr*)&bB[((rB0 * 4 + h2 + kk8) ^ xorv) * 8];
            acc[0] = MFMA32(a0, b0, acc[0]);
            acc[1] = MFMA32(a1, b0, acc[1]);
        }
        if (nxt) {
            const float iv = inv[(it + 1) >> 1];  // h = kt>>6, iter-uniform
            bfr pk;
#pragma unroll
            for (int j = 0; j < 8; ++j)
                pk[j] = f2bf((bf2f(v0[j]) + bf2f(v1[j])) * iv);
            *(bfr*)&As[(1 - p) * 4096 + t * 8] = pk;
        }
    }

    const int n = n0 + wn * 32 + lm;
    const float bn = bias[n];
#pragma unroll
    for (int mt = 0; mt < 2; ++mt) {
        const int mbase = m0 + wm * 64 + mt * 32 + 4 * h2;
#pragma unroll
        for (int r = 0; r < 16; ++r) {
            const int m = mbase + (r & 3) + 8 * (r >> 2);
            out[(size_t)m * 1024 + n] = acc[mt][r] + bn;
        }
    }
}

// ---------- flash attention: 4-buffer counted-vmcnt pipeline (R12/R13) ----
// 32-row KV tiles; per iter: vmcnt(4) -> raw s_barrier -> issue DMA(it+3).
// Buffer layout per 8KB buf: K[0..2047] (one 32-row frag group),
// V dblk0 chunks {2h,2h+1} at [2048..3071], V dblk1 at [3072..4095].
__global__ __launch_bounds__(256, 3) void attn(
    const short* __restrict__ Qf, const short* __restrict__ Kf,
    const short* __restrict__ Vt, short* __restrict__ part,
    float* __restrict__ lsum) {
    __shared__ short smem[16384];  // 4 bufs x 8KB = 32 KB
    const int bid = blockIdx.x;
    const int hidx = bid & 31, qs = bid >> 5;
    const int split = qs & 1, qb = qs >> 1;
    const int b = hidx >> 4, h = hidx & 15;
    const int lane = threadIdx.x & 63, wv = threadIdx.x >> 6;
    const int lm = lane & 31, h2 = lane >> 5;
    const bool hb = h2 != 0;
    const int q0 = qb * 128 + wv * 32;

    const short* qbase =
        Qf + ((size_t)(hidx * 64 + (q0 >> 5))) * 2048 + lane * 8;
    bfr qf[4];
#pragma unroll
    for (int kc = 0; kc < 4; ++kc) qf[kc] = *(const bfr*)(qbase + kc * 512);

    const short* khead = Kf + (size_t)hidx * 131072 + split * 65536;
    const short* vhead = Vt + (size_t)hidx * 131072 + split * 65536;

    // per-wave staging: waves 0,1 stage K (1KB each), waves 2,3 stage V
    // (dblk0 / dblk1, 1KB each). 2 dma16 per wave per iter.
    const short* gbase = ((wv < 2) ? (khead + wv * 1024)
                                   : (vhead + (wv - 2) * 2048)) + lane * 8;
    const int ldst = wv * 1024;
    const bool kwave = (wv < 2);

    // prologue: stage iters 0..2 (6 dma16 in flight per wave)
#pragma unroll
    for (int pit = 0; pit < 3; ++pit) {
        const int go = kwave ? pit * 2048
                             : ((pit >> 1) * 4096 + (pit & 1) * 1024);
        dma16(gbase + go, &smem[pit * 4096 + ldst]);
        dma16(gbase + go + 512, &smem[pit * 4096 + ldst + 512]);
        __builtin_amdgcn_sched_barrier(0);  // pin batch issue order
    }

    accf oa0 = zero16(), oa1 = zero16();
    float la0 = 0.f, la1 = 0.f;

#pragma unroll 1
    for (int it = 0; it < 32; ++it) {
        // batch(it) was issued 3 iters ago; 4 newest (it+1,it+2) stay in
        // flight across the barrier. All waves wait before barrier -> buf(it)
        // fully staged for everyone after it.
        __builtin_amdgcn_sched_barrier(0);
        asm volatile("s_waitcnt vmcnt(4)" ::: "memory");
        __builtin_amdgcn_s_barrier();
        __builtin_amdgcn_sched_barrier(0);
        {
            // issue batch it+3 into buf((it+3)&3): that buffer was last read
            // at iter it-1, strictly before the barrier above. Tail wraps
            // ((it+3)&31) = dummy re-stage into a dead buffer, keeping the
            // outstanding count uniform so vmcnt(4) is exact for all it.
            const int nx = (it + 3) & 31;
            const int go = kwave ? nx * 2048
                                 : ((nx >> 1) * 4096 + (nx & 1) * 1024);
            short* l = &smem[((it + 3) & 3) * 4096 + ldst];
            dma16(gbase + go, l);
            dma16(gbase + go + 512, l + 512);
        }
        const short* kb = &smem[(it & 3) * 4096];
        bfr kf[4], vf0[2], vf1[2];
#pragma unroll
        for (int kc = 0; kc < 4; ++kc)
            kf[kc] = *(const bfr*)&kb[kc * 512 + lane * 8];
#pragma unroll
        for (int kc = 0; kc < 2; ++kc) {
            vf0[kc] = *(const bfr*)&kb[2048 + kc * 512 + lane * 8];
            vf1[kc] = *(const bfr*)&kb[3072 + kc * 512 + lane * 8];
        }
        accf s0 = zero16();
#pragma unroll
        for (int kc = 0; kc < 4; ++kc) s0 = MFMA32(kf[kc], qf[kc], s0);

#pragma unroll
        for (int i = 0; i < 16; ++i) s0[i] = fexp2(s0[i]);
#pragma unroll
        for (int i = 0; i < 16; ++i) {
            if (i & 1) la1 += s0[i];
            else       la0 += s0[i];
        }

        // packed half-swap transpose (s0-only: k-slots 2h, 2h+1)
        bfr pb[2];
#pragma unroll
        for (int kc = 0; kc < 2; ++kc) {
            const int base = 8 * kc;
            unsigned Lw0 = __builtin_amdgcn_perm(__float_as_uint(s0[base + 1]),
                                                 __float_as_uint(s0[base + 0]),
                                                 0x07060302u);
            unsigned Lw1 = __builtin_amdgcn_perm(__float_as_uint(s0[base + 3]),
                                                 __float_as_uint(s0[base + 2]),
                                                 0x07060302u);
            unsigned Hw0 = __builtin_amdgcn_perm(__float_as_uint(s0[base + 5]),
                                                 __float_as_uint(s0[base + 4]),
                                                 0x07060302u);
            unsigned Hw1 = __builtin_amdgcn_perm(__float_as_uint(s0[base + 7]),
                                                 __float_as_uint(s0[base + 6]),
                                                 0x07060302u);
            unsigned c0 = hb ? Lw0 : Hw0;
            unsigned c1 = hb ? Lw1 : Hw1;
            unsigned r0 = (unsigned)__shfl_xor((int)c0, 32);
            unsigned r1 = (unsigned)__shfl_xor((int)c1, 32);
            u4v pw = {hb ? r0 : Lw0, hb ? r1 : Lw1,
                      hb ? Hw0 : r0, hb ? Hw1 : r1};
            pb[kc] = __builtin_bit_cast(bfr, pw);
        }

#pragma unroll
        for (int kc = 0; kc < 2; ++kc) {
            oa0 = MFMA32(vf0[kc], pb[kc], oa0);
            oa1 = MFMA32(vf1[kc], pb[kc], oa1);
        }
    }

    // drain the wrapped-tail DMAs: kernel must not end with LDS-DMA in
    // flight (LDS may be reallocated to a newly launched block).
    asm volatile("s_waitcnt vmcnt(0)" ::: "memory");
    __builtin_amdgcn_sched_barrier(0);

    float ls = la0 + la1;
    ls += __shfl_xor(ls, 32);
    if (!hb) lsum[((size_t)(split * 2 + b) * 16 + h) * 2048 + q0 + lm] = ls;

    short* orow = part + (size_t)split * 4194304 +
                  (size_t)(b * 2048 + q0 + lm) * 1024 + h * 64;
#pragma unroll
    for (int dt = 0; dt < 2; ++dt) {
        const accf& oa = dt ? oa1 : oa0;
#pragma unroll
        for (int g = 0; g < 4; ++g) {
            const int d0 = dt * 32 + 4 * h2 + 8 * g;
            s4v p = {f2bf(oa[4 * g + 0]), f2bf(oa[4 * g + 1]),
                     f2bf(oa[4 * g + 2]), f2bf(oa[4 * g + 3])};
            *(s4v*)(orow + d0) = p;
        }
    }
}

}  // namespace

extern "C" void kernel_launch(void* const* d_in, const int* in_sizes, int n_in,
                              void* d_out, int out_size, void* d_ws,
                              size_t ws_size, hipStream_t stream) {
    const float* x   = (const float*)d_in[0];
    const float* ctx = (const float*)d_in[1];
    const float* Wq  = (const float*)d_in[2];
    const float* bq  = (const float*)d_in[3];
    const float* Wk  = (const float*)d_in[4];
    const float* bk  = (const float*)d_in[5];
    const float* Wv  = (const float*)d_in[6];
    const float* bv  = (const float*)d_in[7];
    const float* Wo  = (const float*)d_in[8];
    const float* bo  = (const float*)d_in[9];

    short* xb  = (short*)d_ws;
    short* cb  = xb + (size_t)4096 * 1024;
    short* Wqt = cb + (size_t)4096 * 768;
    short* Wkt = Wqt + (size_t)1024 * 1024;
    short* Wvt = Wkt + (size_t)1024 * 768;
    short* Wot = Wvt + (size_t)1024 * 768;
    short* Qf  = Wot + (size_t)1024 * 1024;  // frag-order, pre-scaled
    short* Kf  = Qf + (size_t)4096 * 1024;   // frag-order
    short* Vt  = Kf + (size_t)4096 * 1024;   // frag-order V^T
    short* p0  = Vt + (size_t)4096 * 1024;   // split partials (unnormalized)
    short* p1  = p0 + (size_t)4096 * 1024;
    float* lsum = (float*)(p1 + (size_t)4096 * 1024);  // [2][2][16][2048]

    prep<<<8192, 256, 0, stream>>>(x, ctx, xb, cb, Wq, Wk, Wv, Wo,
                                   Wqt, Wkt, Wvt, Wot);

    const float qscale = 0.125f * 1.44269504088896f;
    gemm_qkv<<<768, 256, 0, stream>>>(xb, cb, Wqt, Wkt, Wvt,
                                      bq, bk, bv, Qf, Kf, Vt, qscale);

    attn<<<1024, 256, 0, stream>>>(Qf, Kf, Vt, p0, lsum);

    gemm_out<<<256, 512, 0, stream>>>(p0, p1, lsum, Wot, bo, (float*)d_out);
}